// Round 1
// baseline (428.218 us; speedup 1.0000x reference)
//
#include <hip/hip_runtime.h>

// ---------------------------------------------------------------------------
// GCN 3-layer forward: N=50000 nodes, E=600000 edges, dims 128 -> 128 -> 64 -> 16
// Pipeline:
//   1. cnt[dst]++ (atomic histogram)            -> degree counts
//   2. dinv[i] = rsqrt(cnt[i]+1)                -> symmetric norm (self-loop incl.)
//   3. alloc: block-scan + 1 atomic/block       -> row_start/cursor (CSR slots)
//   4. scatter: cursor atomics                  -> csr_src, csr_w = dinv[s]*dinv[d]
//   5. per layer: f32 GEMM (h = act @ W), then CSR aggregation
//        out[i] = sum_e csr_w[e]*h[src_e] + dinv[i]^2*h[i] + b  (+ReLU L1,L2)
// CSR is built once and reused by all three layers.
// ---------------------------------------------------------------------------

__global__ void count_kernel(const int* __restrict__ dst, int* __restrict__ cnt, int E) {
  int e = blockIdx.x * blockDim.x + threadIdx.x;
  if (e < E) atomicAdd(&cnt[dst[e]], 1);
}

__global__ void dinv_kernel(const int* __restrict__ cnt, float* __restrict__ dinv, int n) {
  int i = blockIdx.x * blockDim.x + threadIdx.x;
  if (i < n) dinv[i] = rsqrtf((float)cnt[i] + 1.0f);
}

// Per-block exclusive scan of counts + single atomic per block to allocate
// contiguous CSR slot ranges (row order across blocks is arbitrary; fine).
__global__ void alloc_kernel(const int* __restrict__ cnt, int* __restrict__ row_start,
                             int* __restrict__ cursor, int* __restrict__ counter, int n) {
  __shared__ int sbuf[256];
  __shared__ int sbase;
  int t = threadIdx.x;
  int node = blockIdx.x * 256 + t;
  int c = (node < n) ? cnt[node] : 0;
  sbuf[t] = c;
  __syncthreads();
#pragma unroll
  for (int offs = 1; offs < 256; offs <<= 1) {
    int v = sbuf[t];
    int add = (t >= offs) ? sbuf[t - offs] : 0;
    __syncthreads();
    sbuf[t] = v + add;
    __syncthreads();
  }
  if (t == 255) sbase = atomicAdd(counter, sbuf[255]);  // sbuf[255] == block total
  __syncthreads();
  if (node < n) {
    int excl = sbuf[t] - c;
    row_start[node] = sbase + excl;
    cursor[node] = sbase + excl;
  }
}

__global__ void scatter_kernel(const int* __restrict__ src, const int* __restrict__ dst,
                               const float* __restrict__ dinv, int* __restrict__ cursor,
                               int* __restrict__ csr_src, float* __restrict__ csr_w, int E) {
  int e = blockIdx.x * blockDim.x + threadIdx.x;
  if (e < E) {
    int s = src[e];
    int d = dst[e];
    int pos = atomicAdd(&cursor[d], 1);
    csr_src[pos] = s;
    csr_w[pos] = dinv[s] * dinv[d];
  }
}

// f32 GEMM: C[n x F] = A[n x K] @ W[K x F].  K,F in {128,64,16}, K small so W is
// LDS-staged in 32-row chunks; A staged in 64x32 padded tiles. Each thread owns
// a RT x 4 register micro-tile.
template <int K, int F>
__global__ void gemm_kernel(const float* __restrict__ A, const float* __restrict__ W,
                            float* __restrict__ C, int n) {
  constexpr int BR = 64;
  constexpr int BK = 32;
  constexpr int CG = F / 4;        // col groups of 4
  constexpr int RGROUPS = 256 / CG;
  constexpr int RT = BR / RGROUPS; // rows per thread: F=128->8, 64->4, 16->1
  constexpr int AP = BK + 4;       // pad to keep 16B alignment + rotate banks

  __shared__ float As[BR * AP];
  __shared__ float Ws[BK * F];

  int t = threadIdx.x;
  int rb = blockIdx.x * BR;
  int tx = t % CG;
  int ty = t / CG;

  float acc[RT][4];
#pragma unroll
  for (int i = 0; i < RT; i++)
#pragma unroll
    for (int j = 0; j < 4; j++) acc[i][j] = 0.0f;

  for (int kc = 0; kc < K; kc += BK) {
    // stage A tile: 64 rows x 32 k, float4 per thread x2
#pragma unroll
    for (int rep = 0; rep < 2; rep++) {
      int row = rep * 32 + t / 8;
      int kk = (t % 8) * 4;
      int gr = rb + row;
      float4 val = make_float4(0.f, 0.f, 0.f, 0.f);
      if (gr < n) val = *(const float4*)&A[(size_t)gr * K + kc + kk];
      *(float4*)&As[row * AP + kk] = val;
    }
    // stage W chunk: BK x F contiguous
    constexpr int WTOT = BK * F / 4;
    const float4* wg = (const float4*)(W + (size_t)kc * F);
    for (int i = t; i < WTOT; i += 256) ((float4*)Ws)[i] = wg[i];
    __syncthreads();

#pragma unroll
    for (int k = 0; k < BK; k++) {
      float4 w = *(const float4*)&Ws[k * F + tx * 4];
#pragma unroll
      for (int i = 0; i < RT; i++) {
        float a = As[(ty * RT + i) * AP + k];
        acc[i][0] = fmaf(a, w.x, acc[i][0]);
        acc[i][1] = fmaf(a, w.y, acc[i][1]);
        acc[i][2] = fmaf(a, w.z, acc[i][2]);
        acc[i][3] = fmaf(a, w.w, acc[i][3]);
      }
    }
    __syncthreads();
  }

#pragma unroll
  for (int i = 0; i < RT; i++) {
    int r = rb + ty * RT + i;
    if (r < n) {
      float4 v = make_float4(acc[i][0], acc[i][1], acc[i][2], acc[i][3]);
      *(float4*)&C[(size_t)r * F + tx * 4] = v;
    }
  }
}

// CSR aggregation: TPN threads cooperate on one node's F features.
// out[i] = sum_e w_e * h[src_e] + dinv[i]^2 * h[i] + bias  (+ReLU)
template <int F, int TPN, bool RELU>
__global__ void agg_kernel(const float* __restrict__ h, const int* __restrict__ row_start,
                           const int* __restrict__ cnt, const int* __restrict__ csr_src,
                           const float* __restrict__ csr_w, const float* __restrict__ dinv,
                           const float* __restrict__ bias, float* __restrict__ out, int n) {
  constexpr int NPB = 256 / TPN;
  constexpr int VPT = F / TPN;
  int node = blockIdx.x * NPB + threadIdx.x / TPN;
  int lane = threadIdx.x % TPN;
  if (node >= n) return;

  float di = dinv[node];
  float self = di * di;
  float acc[VPT];
  const float* hn = &h[(size_t)node * F + lane * VPT];
#pragma unroll
  for (int v = 0; v < VPT; v++) acc[v] = hn[v] * self;

  int s = row_start[node];
  int e = s + cnt[node];
  for (int j = s; j < e; j++) {
    int src = csr_src[j];
    float w = csr_w[j];
    const float* hp = &h[(size_t)src * F + lane * VPT];
#pragma unroll
    for (int v = 0; v < VPT; v++) acc[v] = fmaf(hp[v], w, acc[v]);
  }

  float* op = &out[(size_t)node * F + lane * VPT];
#pragma unroll
  for (int v = 0; v < VPT; v++) {
    float r = acc[v] + bias[lane * VPT + v];
    if (RELU) r = fmaxf(r, 0.0f);
    op[v] = r;
  }
}

extern "C" void kernel_launch(void* const* d_in, const int* in_sizes, int n_in,
                              void* d_out, int out_size, void* d_ws, size_t ws_size,
                              hipStream_t stream) {
  const float* x = (const float*)d_in[0];
  const int* edge = (const int*)d_in[1];
  const float* W1 = (const float*)d_in[2];
  const float* b1 = (const float*)d_in[3];
  const float* W2 = (const float*)d_in[4];
  const float* b2 = (const float*)d_in[5];
  const float* W3 = (const float*)d_in[6];
  const float* b3 = (const float*)d_in[7];

  const int N = in_sizes[0] / 128;
  const int E = in_sizes[1] / 2;
  const int* src = edge;      // edge_index[0]
  const int* dstp = edge + E; // edge_index[1]
  float* out = (float*)d_out;

  // workspace carve-up (256B aligned)
  size_t off = 0;
  auto take = [&](size_t bytes) -> void* {
    void* r = (char*)d_ws + off;
    off += (bytes + 255) & ~(size_t)255;
    return r;
  };
  int* counter = (int*)take(4);
  int* cnt = (int*)take((size_t)N * 4);
  float* dinv = (float*)take((size_t)N * 4);
  int* row_start = (int*)take((size_t)N * 4);
  int* cursor = (int*)take((size_t)N * 4);
  int* csr_src = (int*)take((size_t)E * 4);
  float* csr_w = (float*)take((size_t)E * 4);
  float* bufh = (float*)take((size_t)N * 128 * 4);
  float* bufa = (float*)take((size_t)N * 128 * 4);

  // zero counter + cnt (they're the first two regions, contiguous)
  hipMemsetAsync(d_ws, 0, 256 + (size_t)N * 4, stream);

  const int TB = 256;
  int eg = (E + TB - 1) / TB;
  int ng = (N + TB - 1) / TB;

  count_kernel<<<eg, TB, 0, stream>>>(dstp, cnt, E);
  dinv_kernel<<<ng, TB, 0, stream>>>(cnt, dinv, N);
  alloc_kernel<<<ng, TB, 0, stream>>>(cnt, row_start, cursor, counter, N);
  scatter_kernel<<<eg, TB, 0, stream>>>(src, dstp, dinv, cursor, csr_src, csr_w, E);

  // Layer 1: 128 -> 128, ReLU
  gemm_kernel<128, 128><<<(N + 63) / 64, 256, 0, stream>>>(x, W1, bufh, N);
  agg_kernel<128, 64, true><<<(N + 3) / 4, 256, 0, stream>>>(bufh, row_start, cnt, csr_src,
                                                             csr_w, dinv, b1, bufa, N);
  // Layer 2: 128 -> 64, ReLU
  gemm_kernel<128, 64><<<(N + 63) / 64, 256, 0, stream>>>(bufa, W2, bufh, N);
  agg_kernel<64, 64, true><<<(N + 3) / 4, 256, 0, stream>>>(bufh, row_start, cnt, csr_src,
                                                            csr_w, dinv, b2, bufa, N);
  // Layer 3: 64 -> 16, no ReLU
  gemm_kernel<64, 16><<<(N + 63) / 64, 256, 0, stream>>>(bufa, W3, bufh, N);
  agg_kernel<16, 16, false><<<(N + 15) / 16, 256, 0, stream>>>(bufh, row_start, cnt, csr_src,
                                                               csr_w, dinv, b3, out, N);
}

// Round 2
// 333.085 us; speedup vs baseline: 1.2856x; 1.2856x over previous
//
#include <hip/hip_runtime.h>

// ---------------------------------------------------------------------------
// GCN 3-layer forward: N=50000, E=600000, dims 128 -> 128 -> 64 -> 16.
// CSR (packed int2 {src, w}) built once per call, reused by all layers.
// GEMM: f32, 256 thr, RT rows x 4 cols micro-tile, k-quad float4 LDS reads,
//       double-buffered LDS staged via global_load_lds (async, width 16).
// AGG:  TPN = F/4 lanes per node, float4 gathers, 2-edge unroll.
// ---------------------------------------------------------------------------

__device__ inline void fmaw(float4& acc, float a, const float4& w) {
  acc.x = fmaf(a, w.x, acc.x);
  acc.y = fmaf(a, w.y, acc.y);
  acc.z = fmaf(a, w.z, acc.z);
  acc.w = fmaf(a, w.w, acc.w);
}

__device__ inline void fma4(float4& acc, const float4& g, float w) {
  acc.x = fmaf(g.x, w, acc.x);
  acc.y = fmaf(g.y, w, acc.y);
  acc.z = fmaf(g.z, w, acc.z);
  acc.w = fmaf(g.w, w, acc.w);
}

__device__ inline void async_cp16(const float* g, float* l) {
  __builtin_amdgcn_global_load_lds((const __attribute__((address_space(1))) void*)g,
                                   (__attribute__((address_space(3))) void*)l, 16, 0, 0);
}

// ------------------------------- CSR build ---------------------------------

__global__ void count_kernel(const int* __restrict__ dst, int* __restrict__ cnt, int E) {
  int e = blockIdx.x * blockDim.x + threadIdx.x;
  if (e < E) atomicAdd(&cnt[dst[e]], 1);
}

__global__ void dinv_kernel(const int* __restrict__ cnt, float* __restrict__ dinv, int n) {
  int i = blockIdx.x * blockDim.x + threadIdx.x;
  if (i < n) dinv[i] = rsqrtf((float)cnt[i] + 1.0f);
}

__global__ void alloc_kernel(const int* __restrict__ cnt, int* __restrict__ row_start,
                             int* __restrict__ cursor, int* __restrict__ counter, int n) {
  __shared__ int sbuf[256];
  __shared__ int sbase;
  int t = threadIdx.x;
  int node = blockIdx.x * 256 + t;
  int c = (node < n) ? cnt[node] : 0;
  sbuf[t] = c;
  __syncthreads();
#pragma unroll
  for (int offs = 1; offs < 256; offs <<= 1) {
    int v = sbuf[t];
    int add = (t >= offs) ? sbuf[t - offs] : 0;
    __syncthreads();
    sbuf[t] = v + add;
    __syncthreads();
  }
  if (t == 255) sbase = atomicAdd(counter, sbuf[255]);
  __syncthreads();
  if (node < n) {
    int excl = sbuf[t] - c;
    row_start[node] = sbase + excl;
    cursor[node] = sbase + excl;
  }
}

__global__ void scatter_kernel(const int* __restrict__ src, const int* __restrict__ dst,
                               const float* __restrict__ dinv, int* __restrict__ cursor,
                               int2* __restrict__ csr, int E) {
  int e = blockIdx.x * blockDim.x + threadIdx.x;
  if (e < E) {
    int s = src[e];
    int d = dst[e];
    int pos = atomicAdd(&cursor[d], 1);
    int2 pk;
    pk.x = s;
    pk.y = __float_as_int(dinv[s] * dinv[d]);
    csr[pos] = pk;
  }
}

// --------------------------------- GEMM ------------------------------------
// C[n x F] = A[n x K] @ W[K x F].  Micro-tile RT rows x 4 cols per thread.
// A LDS layout: [kquad 0..7][row 0..BR-1][4 k-floats]  (linear for load_lds,
// and per-wave A reads are broadcast / <=4-way bank aliased).
// W LDS layout: [k][F] row-major (linear).
template <int K, int F, int RT>
__global__ __launch_bounds__(256, 4) void gemm_kernel(const float* __restrict__ A,
                                                      const float* __restrict__ W,
                                                      float* __restrict__ C, int n) {
  constexpr int CG = F / 4;        // col groups
  constexpr int RG = 256 / CG;     // row groups
  constexpr int BR = RG * RT;      // rows per block
  constexpr int BK = 32;
  constexpr int CHUNKS = K / BK;
  constexpr int AQ = BR / 8;       // 1KB wave-instrs for A tile (BR*128B)
  constexpr int WQ = F / 8;        // 1KB wave-instrs for W chunk (F*128B)

  __shared__ float As[2][BR * BK];
  __shared__ float Ws[2][BK * F];

  int t = threadIdx.x;
  int wid = t >> 6;
  int lane = t & 63;
  int tx = t % CG;
  int ty = t / CG;
  int rb = blockIdx.x * BR;

  auto stage = [&](int buf, int kc) {
    // A tile: lane-linear 16B chunks; element q=(m*64+lane) -> row=q%BR, quad=q/BR
    for (int m = wid; m < AQ; m += 4) {
      int q = m * 64 + lane;
      int row = q % BR;
      int kq = q / BR;
      int gr = rb + row;
      const float* gp = A + (size_t)gr * K + kc + kq * 4;
      float* lp = &As[buf][m * 256];  // wave-uniform base; HW adds lane*16
      if (gr < n) async_cp16(gp, lp);
    }
    // W chunk: contiguous 32 x F
    for (int m = wid; m < WQ; m += 4) {
      const float* gp = W + (size_t)kc * F + (size_t)(m * 64 + lane) * 4;
      float* lp = &Ws[buf][m * 256];
      async_cp16(gp, lp);
    }
  };

  float4 acc[RT];
#pragma unroll
  for (int i = 0; i < RT; i++) acc[i] = make_float4(0.f, 0.f, 0.f, 0.f);

  stage(0, 0);
  for (int c = 0; c < CHUNKS; ++c) {
    __syncthreads();  // drains vmcnt: buf[c&1] staged; prev compute done
    if (c + 1 < CHUNKS) stage((c + 1) & 1, (c + 1) * BK);
    const float* as = As[c & 1];
    const float* ws = Ws[c & 1];
#pragma unroll
    for (int kq = 0; kq < 8; ++kq) {
      float4 w0 = *(const float4*)&ws[(kq * 4 + 0) * F + tx * 4];
      float4 w1 = *(const float4*)&ws[(kq * 4 + 1) * F + tx * 4];
      float4 w2 = *(const float4*)&ws[(kq * 4 + 2) * F + tx * 4];
      float4 w3 = *(const float4*)&ws[(kq * 4 + 3) * F + tx * 4];
#pragma unroll
      for (int i = 0; i < RT; ++i) {
        float4 a = *(const float4*)&as[(kq * BR + ty * RT + i) * 4];
        fmaw(acc[i], a.x, w0);
        fmaw(acc[i], a.y, w1);
        fmaw(acc[i], a.z, w2);
        fmaw(acc[i], a.w, w3);
      }
    }
  }

#pragma unroll
  for (int i = 0; i < RT; ++i) {
    int r = rb + ty * RT + i;
    if (r < n) *(float4*)&C[(size_t)r * F + tx * 4] = acc[i];
  }
}

// ------------------------------ Aggregation --------------------------------
// out[i] = sum_e w_e * h[src_e] + dinv[i]^2 * h[i] + bias   (+ReLU)
template <int F, bool RELU>
__global__ __launch_bounds__(256) void agg_kernel(
    const float* __restrict__ h, const int* __restrict__ row_start,
    const int* __restrict__ cnt, const int2* __restrict__ csr,
    const float* __restrict__ dinv, const float* __restrict__ bias,
    float* __restrict__ out, int n) {
  constexpr int TPN = F / 4;       // lanes per node
  constexpr int NPB = 256 / TPN;   // nodes per block
  int node = blockIdx.x * NPB + threadIdx.x / TPN;
  int lane = threadIdx.x % TPN;
  if (node >= n) return;

  float di = dinv[node];
  float sc = di * di;
  float4 hs = *(const float4*)&h[(size_t)node * F + lane * 4];
  float4 acc = make_float4(hs.x * sc, hs.y * sc, hs.z * sc, hs.w * sc);

  int s = row_start[node];
  int e = s + cnt[node];
  int j = s;
  for (; j + 2 <= e; j += 2) {
    int2 p0 = csr[j];
    int2 p1 = csr[j + 1];
    float4 g0 = *(const float4*)&h[(size_t)p0.x * F + lane * 4];
    float4 g1 = *(const float4*)&h[(size_t)p1.x * F + lane * 4];
    fma4(acc, g0, __int_as_float(p0.y));
    fma4(acc, g1, __int_as_float(p1.y));
  }
  if (j < e) {
    int2 p = csr[j];
    float4 g = *(const float4*)&h[(size_t)p.x * F + lane * 4];
    fma4(acc, g, __int_as_float(p.y));
  }

  float4 b4 = *(const float4*)&bias[lane * 4];
  float4 r = make_float4(acc.x + b4.x, acc.y + b4.y, acc.z + b4.z, acc.w + b4.w);
  if (RELU) {
    r.x = fmaxf(r.x, 0.f);
    r.y = fmaxf(r.y, 0.f);
    r.z = fmaxf(r.z, 0.f);
    r.w = fmaxf(r.w, 0.f);
  }
  *(float4*)&out[(size_t)node * F + lane * 4] = r;
}

// -------------------------------- launch -----------------------------------

extern "C" void kernel_launch(void* const* d_in, const int* in_sizes, int n_in,
                              void* d_out, int out_size, void* d_ws, size_t ws_size,
                              hipStream_t stream) {
  const float* x = (const float*)d_in[0];
  const int* edge = (const int*)d_in[1];
  const float* W1 = (const float*)d_in[2];
  const float* b1 = (const float*)d_in[3];
  const float* W2 = (const float*)d_in[4];
  const float* b2 = (const float*)d_in[5];
  const float* W3 = (const float*)d_in[6];
  const float* b3 = (const float*)d_in[7];

  const int N = in_sizes[0] / 128;
  const int E = in_sizes[1] / 2;
  const int* src = edge;       // edge_index[0]
  const int* dstp = edge + E;  // edge_index[1]
  float* out = (float*)d_out;

  size_t off = 0;
  auto take = [&](size_t bytes) -> void* {
    void* r = (char*)d_ws + off;
    off += (bytes + 255) & ~(size_t)255;
    return r;
  };
  int* counter = (int*)take(4);
  int* cnt = (int*)take((size_t)N * 4);
  float* dinv = (float*)take((size_t)N * 4);
  int* row_start = (int*)take((size_t)N * 4);
  int* cursor = (int*)take((size_t)N * 4);
  int2* csr = (int2*)take((size_t)E * 8);
  float* bufh = (float*)take((size_t)N * 128 * 4);
  float* bufa = (float*)take((size_t)N * 128 * 4);

  // zero counter + cnt (first two regions, contiguous)
  hipMemsetAsync(d_ws, 0, 256 + (size_t)N * 4, stream);

  const int TB = 256;
  int eg = (E + TB - 1) / TB;
  int ng = (N + TB - 1) / TB;

  count_kernel<<<eg, TB, 0, stream>>>(dstp, cnt, E);
  dinv_kernel<<<ng, TB, 0, stream>>>(cnt, dinv, N);
  alloc_kernel<<<ng, TB, 0, stream>>>(cnt, row_start, cursor, counter, N);
  scatter_kernel<<<eg, TB, 0, stream>>>(src, dstp, dinv, cursor, csr, E);

  // Layer 1: 128 -> 128 (+ReLU).  RT=8 -> BR=64, grid 782.
  gemm_kernel<128, 128, 8><<<(N + 63) / 64, 256, 0, stream>>>(x, W1, bufh, N);
  agg_kernel<128, true><<<(N + 7) / 8, 256, 0, stream>>>(bufh, row_start, cnt, csr, dinv, b1,
                                                         bufa, N);
  // Layer 2: 128 -> 64 (+ReLU).  RT=4 -> BR=64, grid 782.
  gemm_kernel<128, 64, 4><<<(N + 63) / 64, 256, 0, stream>>>(bufa, W2, bufh, N);
  agg_kernel<64, true><<<(N + 15) / 16, 256, 0, stream>>>(bufh, row_start, cnt, csr, dinv, b2,
                                                          bufa, N);
  // Layer 3: 64 -> 16.  RT=2 -> BR=128, grid 391.
  gemm_kernel<64, 16, 2><<<(N + 127) / 128, 256, 0, stream>>>(bufa, W3, bufh, N);
  agg_kernel<16, false><<<(N + 63) / 64, 256, 0, stream>>>(bufh, row_start, cnt, csr, dinv, b3,
                                                           out, N);
}